// Round 10
// baseline (242.066 us; speedup 1.0000x reference)
//
#include <hip/hip_runtime.h>
#include <math.h>

#define B_N 256
#define V_N 6890
#define J_N 24
#define KPF 207
#define KE  218
#define NCOL (V_N*3)   // 20670

__device__ __constant__ int c_par[24] = {-1,0,0,0,1,2,3,4,5,6,7,8,9,9,9,12,13,14,16,17,18,19,20,21};

// ws layout (floats)
#define WS_PF   0
#define WS_A    (WS_PF + B_N*KE)                 // 55808 (PF stored transposed [KE][B_N])
#define WS_EXT  (WS_A + B_N*J_N*12)              // 129536
#define WS_PART (WS_EXT + 11*NCOL)               // 356906 (96*33 = 3168)

// ---------------- stage 0a: partial joint-regressor contraction ----------------
__global__ __launch_bounds__(256) void k_jreg(const float* __restrict__ Jreg,
        const float* __restrict__ vt, const float* __restrict__ sd,
        float* __restrict__ part)
{
    int j = blockIdx.x;
    int c = blockIdx.y;
    int tid = threadIdx.x;
    int v0 = c * 1723;
    int v1 = v0 + 1723; if (v1 > V_N) v1 = V_N;

    float acc[33];
    #pragma unroll
    for (int i = 0; i < 33; ++i) acc[i] = 0.f;

    for (int v = v0 + tid; v < v1; v += 256) {
        float r = Jreg[j*V_N + v];
        const float* s = sd + v*30;
        #pragma unroll
        for (int i = 0; i < 30; ++i) acc[i] += r * s[i];
        #pragma unroll
        for (int k = 0; k < 3; ++k) acc[30+k] += r * vt[v*3+k];
    }
    #pragma unroll
    for (int i = 0; i < 33; ++i) {
        #pragma unroll
        for (int off = 32; off > 0; off >>= 1)
            acc[i] += __shfl_down(acc[i], off, 64);
    }
    __shared__ float red[4][33];
    int wave = tid >> 6, lane = tid & 63;
    if (lane == 0) {
        #pragma unroll
        for (int i = 0; i < 33; ++i) red[wave][i] = acc[i];
    }
    __syncthreads();
    if (tid < 33) {
        float s = red[0][tid] + red[1][tid] + red[2][tid] + red[3][tid];
        part[(j*4 + c)*33 + tid] = s;
    }
}

// ---------------- stage 0b: build extended "posedirs" rows 207..217 ----------------
__global__ __launch_bounds__(256) void k_ext(const float* __restrict__ sd,
        const float* __restrict__ vt, float* __restrict__ EXT)
{
    int idx = blockIdx.x*256 + threadIdx.x;
    if (idx >= NCOL) return;
    int v = idx / 3, k = idx - v*3;
    #pragma unroll
    for (int l = 0; l < 10; ++l) EXT[l*NCOL + idx] = sd[v*30 + k*10 + l];
    EXT[10*NCOL + idx] = vt[idx];
}

// ---------------- stage 1: per-batch Rodrigues + kinematic chain (+ folded jred) ----------------
// PF is written TRANSPOSED: PFt[r*B_N + b]
__global__ __launch_bounds__(64) void k_batch(const float* __restrict__ pose,
        const float* __restrict__ betas, const float* __restrict__ part,
        float* __restrict__ PFt, float* __restrict__ A, float* __restrict__ outJ)
{
    int b = blockIdx.x;
    int lane = threadIdx.x;
    __shared__ float sR[24][9];
    __shared__ float sJ[24][3];
    __shared__ float sG[24][12];

    if (lane < 24) {
        float R[9];
        if (lane < 22) {
            float p0 = pose[b*72 + lane*3 + 0];
            float p1 = pose[b*72 + lane*3 + 1];
            float p2 = pose[b*72 + lane*3 + 2];
            float a0 = p0 + 1e-8f, a1 = p1 + 1e-8f, a2 = p2 + 1e-8f;
            float angle = sqrtf(a0*a0 + a1*a1 + a2*a2);
            float inv = 1.f / angle;
            float rx = p0*inv, ry = p1*inv, rz = p2*inv;
            float cc = cosf(angle), ss = sinf(angle), ic = 1.f - cc;
            R[0] = 1.f - ic*(ry*ry + rz*rz);
            R[1] = -ss*rz + ic*rx*ry;
            R[2] =  ss*ry + ic*rx*rz;
            R[3] =  ss*rz + ic*rx*ry;
            R[4] = 1.f - ic*(rx*rx + rz*rz);
            R[5] = -ss*rx + ic*ry*rz;
            R[6] = -ss*ry + ic*rx*rz;
            R[7] =  ss*rx + ic*ry*rz;
            R[8] = 1.f - ic*(rx*rx + ry*ry);
        } else {
            R[0]=1.f;R[1]=0.f;R[2]=0.f;R[3]=0.f;R[4]=1.f;R[5]=0.f;R[6]=0.f;R[7]=0.f;R[8]=1.f;
        }
        #pragma unroll
        for (int e = 0; e < 9; ++e) sR[lane][e] = R[e];
    }
    __syncthreads();
    for (int idx = lane; idx < 72; idx += 64) {
        int j = idx / 3, k = idx - j*3;
        const float* p0 = part + (j*4 + 0)*33;
        const float* p1 = part + (j*4 + 1)*33;
        const float* p2 = part + (j*4 + 2)*33;
        const float* p3 = part + (j*4 + 3)*33;
        float s = p0[30+k] + p1[30+k] + p2[30+k] + p3[30+k];
        #pragma unroll
        for (int l = 0; l < 10; ++l) {
            float js = p0[k*10+l] + p1[k*10+l] + p2[k*10+l] + p3[k*10+l];
            s += betas[b*10+l] * js;
        }
        sJ[j][k] = s;
    }
    __syncthreads();
    for (int idx = lane; idx < KPF; idx += 64) {
        int jj = 1 + idx/9, e = idx - (idx/9)*9;
        float id = (e==0 || e==4 || e==8) ? 1.f : 0.f;
        PFt[idx*B_N + b] = sR[jj][e] - id;
    }
    if (lane < 10) PFt[(KPF+lane)*B_N + b] = betas[b*10 + lane];
    if (lane == 0) PFt[217*B_N + b] = 1.f;

    if (lane == 0) {
        #pragma unroll
        for (int r = 0; r < 3; ++r) {
            sG[0][r*4+0] = sR[0][r*3+0];
            sG[0][r*4+1] = sR[0][r*3+1];
            sG[0][r*4+2] = sR[0][r*3+2];
            sG[0][r*4+3] = sJ[0][r];
        }
        for (int i = 1; i < 24; ++i) {
            int p = c_par[i];
            float rel0 = sJ[i][0]-sJ[p][0], rel1 = sJ[i][1]-sJ[p][1], rel2 = sJ[i][2]-sJ[p][2];
            for (int r = 0; r < 3; ++r) {
                float g0 = sG[p][r*4+0], g1 = sG[p][r*4+1], g2 = sG[p][r*4+2], g3 = sG[p][r*4+3];
                sG[i][r*4+0] = g0*sR[i][0] + g1*sR[i][3] + g2*sR[i][6];
                sG[i][r*4+1] = g0*sR[i][1] + g1*sR[i][4] + g2*sR[i][7];
                sG[i][r*4+2] = g0*sR[i][2] + g1*sR[i][5] + g2*sR[i][8];
                sG[i][r*4+3] = g0*rel0 + g1*rel1 + g2*rel2 + g3;
            }
        }
    }
    __syncthreads();
    if (lane < 24) {
        int i = lane;
        #pragma unroll
        for (int r = 0; r < 3; ++r) {
            float g0 = sG[i][r*4+0], g1 = sG[i][r*4+1], g2 = sG[i][r*4+2], g3 = sG[i][r*4+3];
            outJ[b*72 + i*3 + r] = g3;
            float t = g3 - (g0*sJ[i][0] + g1*sJ[i][1] + g2*sJ[i][2]);
            A[(b*24+i)*12 + r*4+0] = g0;
            A[(b*24+i)*12 + r*4+1] = g1;
            A[(b*24+i)*12 + r*4+2] = g2;
            A[(b*24+i)*12 + r*4+3] = t;
        }
    }
}

// ---------------- stage 2: fused v_posed GEMM + skinning ----------------
// 1-D grid of 864 blocks, XCD-swizzled. Tile: 64 verts x 32 batches;
// thread = (vert=lane, 8 batches = wave*8+k). ZERO LDS, zero barriers:
// wave-uniform data (PF rows, A matrices) read via readfirstlane-uniform pointers
// -> scalar loads (s_load) through the scalar cache; per-lane data (vertex float3, W)
// via coalesced vector loads. FMAs are v_fmac(vgpr, sgpr, vgpr).
__global__ __launch_bounds__(256, 2) void k_fused(
        const float* __restrict__ posedirs, const float* __restrict__ EXT,
        const float* __restrict__ PFt, const float* __restrict__ A,
        const float* __restrict__ W, float* __restrict__ out)
{
    int tid  = threadIdx.x;
    int wave = tid >> 6, lane = tid & 63;

    int bid = blockIdx.x;
    int w   = (bid & 7)*108 + (bid >> 3);
    int vt  = w >> 3, bt = w & 7;
    int v0 = vt * 64;
    int b0 = bt * 32;
    int v  = v0 + lane;

    // clamped per-lane float column within a row (stays in-row for ragged tail)
    int col = (v < V_N) ? v*3 : v0*3;

    // wave-uniform base offsets (readfirstlane -> SGPR -> scalar loads)
    int wu8 = __builtin_amdgcn_readfirstlane(wave * 8);
    const float* __restrict__ pf = PFt + b0 + wu8;               // + r*B_N per row
    const float* __restrict__ Ab0 = A + (size_t)(b0 + wu8) * 288;

    float acc[8][3];
    #pragma unroll
    for (int k = 0; k < 8; ++k) { acc[k][0]=0.f; acc[k][1]=0.f; acc[k][2]=0.f; }

    // main K-loop: per row 1 per-lane dwordx3 + 8 uniform (scalar) floats + 24 fma
    {
        const float* p = posedirs + col;
        #pragma unroll 8
        for (int r = 0; r < KPF; ++r) {
            float x = p[0], y = p[1], z = p[2];
            float f0 = pf[0], f1 = pf[1], f2 = pf[2], f3 = pf[3];
            float f4 = pf[4], f5 = pf[5], f6 = pf[6], f7 = pf[7];
            acc[0][0] += f0*x; acc[0][1] += f0*y; acc[0][2] += f0*z;
            acc[1][0] += f1*x; acc[1][1] += f1*y; acc[1][2] += f1*z;
            acc[2][0] += f2*x; acc[2][1] += f2*y; acc[2][2] += f2*z;
            acc[3][0] += f3*x; acc[3][1] += f3*y; acc[3][2] += f3*z;
            acc[4][0] += f4*x; acc[4][1] += f4*y; acc[4][2] += f4*z;
            acc[5][0] += f5*x; acc[5][1] += f5*y; acc[5][2] += f5*z;
            acc[6][0] += f6*x; acc[6][1] += f6*y; acc[6][2] += f6*z;
            acc[7][0] += f7*x; acc[7][1] += f7*y; acc[7][2] += f7*z;
            p += NCOL; pf += B_N;
        }
    }
    // tail rows 207..217 from EXT (includes betas rows + v_template row, PF=1.0)
    {
        const float* p = EXT + col;
        #pragma unroll
        for (int r = KPF; r < KE; ++r) {
            float x = p[0], y = p[1], z = p[2];
            float f0 = pf[0], f1 = pf[1], f2 = pf[2], f3 = pf[3];
            float f4 = pf[4], f5 = pf[5], f6 = pf[6], f7 = pf[7];
            acc[0][0] += f0*x; acc[0][1] += f0*y; acc[0][2] += f0*z;
            acc[1][0] += f1*x; acc[1][1] += f1*y; acc[1][2] += f1*z;
            acc[2][0] += f2*x; acc[2][1] += f2*y; acc[2][2] += f2*z;
            acc[3][0] += f3*x; acc[3][1] += f3*y; acc[3][2] += f3*z;
            acc[4][0] += f4*x; acc[4][1] += f4*y; acc[4][2] += f4*z;
            acc[5][0] += f5*x; acc[5][1] += f5*y; acc[5][2] += f5*z;
            acc[6][0] += f6*x; acc[6][1] += f6*y; acc[6][2] += f6*z;
            acc[7][0] += f7*x; acc[7][1] += f7*y; acc[7][2] += f7*z;
            p += NCOL; pf += B_N;
        }
    }

    // per-vertex weights (per-lane vector loads, 16B-aligned rows; clamped index)
    int vc = (v < V_N) ? v : (V_N - 1);
    const float4* W4 = reinterpret_cast<const float4*>(W + (size_t)vc*24);
    float4 w0 = W4[0], w1 = W4[1], w2 = W4[2], w3 = W4[3], w4 = W4[4], w5 = W4[5];
    float wv[24] = {w0.x,w0.y,w0.z,w0.w, w1.x,w1.y,w1.z,w1.w, w2.x,w2.y,w2.z,w2.w,
                    w3.x,w3.y,w3.z,w3.w, w4.x,w4.y,w4.z,w4.w, w5.x,w5.y,w5.z,w5.w};

    // FULLY UNROLLED epilogue; A read via wave-uniform pointer (scalar loads)
    #pragma unroll
    for (int k = 0; k < 8; ++k) {
        const float* Ab = Ab0 + k*288;
        float T[12];
        #pragma unroll
        for (int e = 0; e < 12; ++e) T[e] = 0.f;
        #pragma unroll
        for (int j = 0; j < 24; ++j) {
            float ww = wv[j];
            T[0]  += ww*Ab[j*12+0];  T[1]  += ww*Ab[j*12+1];
            T[2]  += ww*Ab[j*12+2];  T[3]  += ww*Ab[j*12+3];
            T[4]  += ww*Ab[j*12+4];  T[5]  += ww*Ab[j*12+5];
            T[6]  += ww*Ab[j*12+6];  T[7]  += ww*Ab[j*12+7];
            T[8]  += ww*Ab[j*12+8];  T[9]  += ww*Ab[j*12+9];
            T[10] += ww*Ab[j*12+10]; T[11] += ww*Ab[j*12+11];
        }
        if (v < V_N) {
            float x = acc[k][0], y = acc[k][1], z = acc[k][2];
            size_t o = (size_t)(b0 + wave*8 + k)*NCOL + (size_t)v*3;
            out[o+0] = T[0]*x + T[1]*y + T[2]*z  + T[3];
            out[o+1] = T[4]*x + T[5]*y + T[6]*z  + T[7];
            out[o+2] = T[8]*x + T[9]*y + T[10]*z + T[11];
        }
    }
}

extern "C" void kernel_launch(void* const* d_in, const int* in_sizes, int n_in,
                              void* d_out, int out_size, void* d_ws, size_t ws_size,
                              hipStream_t stream)
{
    const float* betas      = (const float*)d_in[0];
    const float* pose       = (const float*)d_in[1];
    const float* v_template = (const float*)d_in[2];
    const float* shapedirs  = (const float*)d_in[3];
    const float* posedirs   = (const float*)d_in[4];
    const float* Jreg       = (const float*)d_in[5];
    const float* lbs        = (const float*)d_in[6];

    float* ws   = (float*)d_ws;
    float* PFt  = ws + WS_PF;
    float* A    = ws + WS_A;
    float* EXT  = ws + WS_EXT;
    float* part = ws + WS_PART;

    float* verts = (float*)d_out;
    float* outJ  = verts + (size_t)B_N*V_N*3;

    hipLaunchKernelGGL(k_jreg, dim3(24,4), dim3(256), 0, stream, Jreg, v_template, shapedirs, part);
    hipLaunchKernelGGL(k_ext, dim3((NCOL+255)/256), dim3(256), 0, stream, shapedirs, v_template, EXT);
    hipLaunchKernelGGL(k_batch, dim3(256), dim3(64), 0, stream, pose, betas, part, PFt, A, outJ);
    hipLaunchKernelGGL(k_fused, dim3(8*108), dim3(256), 0, stream, posedirs, EXT, PFt, A, lbs, verts);
}

// Round 11
// 87.411 us; speedup vs baseline: 2.7693x; 2.7693x over previous
//
#include <hip/hip_runtime.h>
#include <math.h>

#define B_N 256
#define V_N 6890
#define J_N 24
#define KPF 207
#define KE  218
#define NCOL (V_N*3)   // 20670

typedef float v2f __attribute__((ext_vector_type(2)));

__device__ __constant__ int c_par[24] = {-1,0,0,0,1,2,3,4,5,6,7,8,9,9,9,12,13,14,16,17,18,19,20,21};

// ws layout (floats)
#define WS_PF   0
#define WS_A    (WS_PF + B_N*KE)                 // 55808 (PF stored transposed [KE][B_N])
#define WS_EXT  (WS_A + B_N*J_N*12)              // 129536
#define WS_PART (WS_EXT + 11*NCOL)               // 356906 (96*33 = 3168)

// ---------------- stage 0a: partial joint-regressor contraction ----------------
__global__ __launch_bounds__(256) void k_jreg(const float* __restrict__ Jreg,
        const float* __restrict__ vt, const float* __restrict__ sd,
        float* __restrict__ part)
{
    int j = blockIdx.x;
    int c = blockIdx.y;
    int tid = threadIdx.x;
    int v0 = c * 1723;
    int v1 = v0 + 1723; if (v1 > V_N) v1 = V_N;

    float acc[33];
    #pragma unroll
    for (int i = 0; i < 33; ++i) acc[i] = 0.f;

    for (int v = v0 + tid; v < v1; v += 256) {
        float r = Jreg[j*V_N + v];
        const float* s = sd + v*30;
        #pragma unroll
        for (int i = 0; i < 30; ++i) acc[i] += r * s[i];
        #pragma unroll
        for (int k = 0; k < 3; ++k) acc[30+k] += r * vt[v*3+k];
    }
    #pragma unroll
    for (int i = 0; i < 33; ++i) {
        #pragma unroll
        for (int off = 32; off > 0; off >>= 1)
            acc[i] += __shfl_down(acc[i], off, 64);
    }
    __shared__ float red[4][33];
    int wave = tid >> 6, lane = tid & 63;
    if (lane == 0) {
        #pragma unroll
        for (int i = 0; i < 33; ++i) red[wave][i] = acc[i];
    }
    __syncthreads();
    if (tid < 33) {
        float s = red[0][tid] + red[1][tid] + red[2][tid] + red[3][tid];
        part[(j*4 + c)*33 + tid] = s;
    }
}

// ---------------- stage 0b: build extended "posedirs" rows 207..217 ----------------
__global__ __launch_bounds__(256) void k_ext(const float* __restrict__ sd,
        const float* __restrict__ vt, float* __restrict__ EXT)
{
    int idx = blockIdx.x*256 + threadIdx.x;
    if (idx >= NCOL) return;
    int v = idx / 3, k = idx - v*3;
    #pragma unroll
    for (int l = 0; l < 10; ++l) EXT[l*NCOL + idx] = sd[v*30 + k*10 + l];
    EXT[10*NCOL + idx] = vt[idx];
}

// ---------------- stage 1: per-batch Rodrigues + kinematic chain (+ folded jred) ----------------
// PF is written TRANSPOSED: PFt[r*B_N + b]
__global__ __launch_bounds__(64) void k_batch(const float* __restrict__ pose,
        const float* __restrict__ betas, const float* __restrict__ part,
        float* __restrict__ PFt, float* __restrict__ A, float* __restrict__ outJ)
{
    int b = blockIdx.x;
    int lane = threadIdx.x;
    __shared__ float sR[24][9];
    __shared__ float sJ[24][3];
    __shared__ float sG[24][12];

    if (lane < 24) {
        float R[9];
        if (lane < 22) {
            float p0 = pose[b*72 + lane*3 + 0];
            float p1 = pose[b*72 + lane*3 + 1];
            float p2 = pose[b*72 + lane*3 + 2];
            float a0 = p0 + 1e-8f, a1 = p1 + 1e-8f, a2 = p2 + 1e-8f;
            float angle = sqrtf(a0*a0 + a1*a1 + a2*a2);
            float inv = 1.f / angle;
            float rx = p0*inv, ry = p1*inv, rz = p2*inv;
            float cc = cosf(angle), ss = sinf(angle), ic = 1.f - cc;
            R[0] = 1.f - ic*(ry*ry + rz*rz);
            R[1] = -ss*rz + ic*rx*ry;
            R[2] =  ss*ry + ic*rx*rz;
            R[3] =  ss*rz + ic*rx*ry;
            R[4] = 1.f - ic*(rx*rx + rz*rz);
            R[5] = -ss*rx + ic*ry*rz;
            R[6] = -ss*ry + ic*rx*rz;
            R[7] =  ss*rx + ic*ry*rz;
            R[8] = 1.f - ic*(rx*rx + ry*ry);
        } else {
            R[0]=1.f;R[1]=0.f;R[2]=0.f;R[3]=0.f;R[4]=1.f;R[5]=0.f;R[6]=0.f;R[7]=0.f;R[8]=1.f;
        }
        #pragma unroll
        for (int e = 0; e < 9; ++e) sR[lane][e] = R[e];
    }
    __syncthreads();
    for (int idx = lane; idx < 72; idx += 64) {
        int j = idx / 3, k = idx - j*3;
        const float* p0 = part + (j*4 + 0)*33;
        const float* p1 = part + (j*4 + 1)*33;
        const float* p2 = part + (j*4 + 2)*33;
        const float* p3 = part + (j*4 + 3)*33;
        float s = p0[30+k] + p1[30+k] + p2[30+k] + p3[30+k];
        #pragma unroll
        for (int l = 0; l < 10; ++l) {
            float js = p0[k*10+l] + p1[k*10+l] + p2[k*10+l] + p3[k*10+l];
            s += betas[b*10+l] * js;
        }
        sJ[j][k] = s;
    }
    __syncthreads();
    for (int idx = lane; idx < KPF; idx += 64) {
        int jj = 1 + idx/9, e = idx - (idx/9)*9;
        float id = (e==0 || e==4 || e==8) ? 1.f : 0.f;
        PFt[idx*B_N + b] = sR[jj][e] - id;
    }
    if (lane < 10) PFt[(KPF+lane)*B_N + b] = betas[b*10 + lane];
    if (lane == 0) PFt[217*B_N + b] = 1.f;

    if (lane == 0) {
        #pragma unroll
        for (int r = 0; r < 3; ++r) {
            sG[0][r*4+0] = sR[0][r*3+0];
            sG[0][r*4+1] = sR[0][r*3+1];
            sG[0][r*4+2] = sR[0][r*3+2];
            sG[0][r*4+3] = sJ[0][r];
        }
        for (int i = 1; i < 24; ++i) {
            int p = c_par[i];
            float rel0 = sJ[i][0]-sJ[p][0], rel1 = sJ[i][1]-sJ[p][1], rel2 = sJ[i][2]-sJ[p][2];
            for (int r = 0; r < 3; ++r) {
                float g0 = sG[p][r*4+0], g1 = sG[p][r*4+1], g2 = sG[p][r*4+2], g3 = sG[p][r*4+3];
                sG[i][r*4+0] = g0*sR[i][0] + g1*sR[i][3] + g2*sR[i][6];
                sG[i][r*4+1] = g0*sR[i][1] + g1*sR[i][4] + g2*sR[i][7];
                sG[i][r*4+2] = g0*sR[i][2] + g1*sR[i][5] + g2*sR[i][8];
                sG[i][r*4+3] = g0*rel0 + g1*rel1 + g2*rel2 + g3;
            }
        }
    }
    __syncthreads();
    if (lane < 24) {
        int i = lane;
        #pragma unroll
        for (int r = 0; r < 3; ++r) {
            float g0 = sG[i][r*4+0], g1 = sG[i][r*4+1], g2 = sG[i][r*4+2], g3 = sG[i][r*4+3];
            outJ[b*72 + i*3 + r] = g3;
            float t = g3 - (g0*sJ[i][0] + g1*sJ[i][1] + g2*sJ[i][2]);
            A[(b*24+i)*12 + r*4+0] = g0;
            A[(b*24+i)*12 + r*4+1] = g1;
            A[(b*24+i)*12 + r*4+2] = g2;
            A[(b*24+i)*12 + r*4+3] = t;
        }
    }
}

// ---------------- stage 2: fused v_posed GEMM + skinning ----------------
// Round-9 structure (LDS broadcast of PF/A, per-lane global vertex stream), with
// all accumulation packed 2-wide -> v_pk_fma_f32 (fp32 packed rate = 2x scalar).
// Tile: 64 verts x 32 batches; thread = (vert=lane, 8 batches = wave*8+k).
__global__ __launch_bounds__(256, 2) void k_fused(
        const float* __restrict__ posedirs, const float* __restrict__ EXT,
        const float* __restrict__ PFt, const float* __restrict__ A,
        const float* __restrict__ W, float* __restrict__ out)
{
    constexpr int BT = 32;
    __shared__ __align__(16) float smem[BT*288];   // 36864 B >= KE*BT (27904 B)

    int tid  = threadIdx.x;
    int wave = tid >> 6, lane = tid & 63;

    int bid = blockIdx.x;
    int w   = (bid & 7)*108 + (bid >> 3);
    int vt  = w >> 3, bt = w & 7;
    int v0 = vt * 64;
    int b0 = bt * BT;
    int v  = v0 + lane;

    int col = (v < V_N) ? v*3 : v0*3;

    // stage PF^T (coalesced reads, conflict-free writes)
    #pragma unroll 1
    for (int idx = tid; idx < KE*BT; idx += 256) {
        int r = idx >> 5, bl = idx & 31;
        smem[r*BT + bl] = PFt[r*B_N + b0 + bl];
    }
    __syncthreads();

    // packed accumulators: (x,y) per batch, z packed across batch pairs
    v2f axy[8];
    v2f az[4];
    #pragma unroll
    for (int k = 0; k < 8; ++k) axy[k] = (v2f){0.f, 0.f};
    #pragma unroll
    for (int k = 0; k < 4; ++k) az[k] = (v2f){0.f, 0.f};

    int pfb = wave*8;

#define ROW_BODY                                                                  \
    {                                                                             \
        float x = p[0], y = p[1], z = p[2];                                       \
        const float4 pa = *reinterpret_cast<const float4*>(&smem[r*BT + pfb]);    \
        const float4 pb = *reinterpret_cast<const float4*>(&smem[r*BT + pfb + 4]);\
        v2f xy = {x, y};                                                          \
        v2f zz = {z, z};                                                          \
        axy[0] = __builtin_elementwise_fma((v2f){pa.x,pa.x}, xy, axy[0]);         \
        axy[1] = __builtin_elementwise_fma((v2f){pa.y,pa.y}, xy, axy[1]);         \
        axy[2] = __builtin_elementwise_fma((v2f){pa.z,pa.z}, xy, axy[2]);         \
        axy[3] = __builtin_elementwise_fma((v2f){pa.w,pa.w}, xy, axy[3]);         \
        axy[4] = __builtin_elementwise_fma((v2f){pb.x,pb.x}, xy, axy[4]);         \
        axy[5] = __builtin_elementwise_fma((v2f){pb.y,pb.y}, xy, axy[5]);         \
        axy[6] = __builtin_elementwise_fma((v2f){pb.z,pb.z}, xy, axy[6]);         \
        axy[7] = __builtin_elementwise_fma((v2f){pb.w,pb.w}, xy, axy[7]);         \
        az[0]  = __builtin_elementwise_fma((v2f){pa.x,pa.y}, zz, az[0]);          \
        az[1]  = __builtin_elementwise_fma((v2f){pa.z,pa.w}, zz, az[1]);          \
        az[2]  = __builtin_elementwise_fma((v2f){pb.x,pb.y}, zz, az[2]);          \
        az[3]  = __builtin_elementwise_fma((v2f){pb.z,pb.w}, zz, az[3]);          \
    }

    {
        const float* p = posedirs + col;
        #pragma unroll 8
        for (int r = 0; r < KPF; ++r) {
            ROW_BODY
            p += NCOL;
        }
    }
    {
        const float* p = EXT + col;
        #pragma unroll
        for (int r = KPF; r < KE; ++r) {
            ROW_BODY
            p += NCOL;
        }
    }
#undef ROW_BODY

    __syncthreads();   // all PF reads done before overwriting smem

    // stage A (32 batches x 288 floats)
    {
        const float* Ag = A + (size_t)b0*288;
        #pragma unroll 1
        for (int idx = tid; idx < BT*288; idx += 256)
            smem[idx] = Ag[idx];
    }

    // per-vertex weights (16B-aligned rows; clamped index, stores masked)
    int vc = (v < V_N) ? v : (V_N - 1);
    const float4* W4 = reinterpret_cast<const float4*>(W + (size_t)vc*24);
    float4 w0 = W4[0], w1 = W4[1], w2 = W4[2], w3 = W4[3], w4 = W4[4], w5 = W4[5];
    __syncthreads();

    float wv[24] = {w0.x,w0.y,w0.z,w0.w, w1.x,w1.y,w1.z,w1.w, w2.x,w2.y,w2.z,w2.w,
                    w3.x,w3.y,w3.z,w3.w, w4.x,w4.y,w4.z,w4.w, w5.x,w5.y,w5.z,w5.w};

    // FULLY UNROLLED epilogue with packed T (6 x v2f per batch)
    #pragma unroll
    for (int k = 0; k < 8; ++k) {
        int bb = wave*8 + k;
        const float* Ab = smem + bb*288;
        v2f T01 = {0.f,0.f}, T23 = {0.f,0.f}, T45 = {0.f,0.f};
        v2f T67 = {0.f,0.f}, T89 = {0.f,0.f}, Tab = {0.f,0.f};
        #pragma unroll
        for (int j = 0; j < 24; ++j) {
            float ww = wv[j];
            v2f wwv = {ww, ww};
            float4 a0 = *reinterpret_cast<const float4*>(Ab + j*12 + 0);
            float4 a1 = *reinterpret_cast<const float4*>(Ab + j*12 + 4);
            float4 a2 = *reinterpret_cast<const float4*>(Ab + j*12 + 8);
            T01 = __builtin_elementwise_fma(wwv, (v2f){a0.x,a0.y}, T01);
            T23 = __builtin_elementwise_fma(wwv, (v2f){a0.z,a0.w}, T23);
            T45 = __builtin_elementwise_fma(wwv, (v2f){a1.x,a1.y}, T45);
            T67 = __builtin_elementwise_fma(wwv, (v2f){a1.z,a1.w}, T67);
            T89 = __builtin_elementwise_fma(wwv, (v2f){a2.x,a2.y}, T89);
            Tab = __builtin_elementwise_fma(wwv, (v2f){a2.z,a2.w}, Tab);
        }
        if (v < V_N) {
            float x = axy[k].x, y = axy[k].y;
            float z = (k & 1) ? az[k>>1].y : az[k>>1].x;
            size_t o = (size_t)(b0 + bb)*NCOL + (size_t)v*3;
            out[o+0] = T01.x*x + T01.y*y + T23.x*z + T23.y;
            out[o+1] = T45.x*x + T45.y*y + T67.x*z + T67.y;
            out[o+2] = T89.x*x + T89.y*y + Tab.x*z + Tab.y;
        }
    }
}

extern "C" void kernel_launch(void* const* d_in, const int* in_sizes, int n_in,
                              void* d_out, int out_size, void* d_ws, size_t ws_size,
                              hipStream_t stream)
{
    const float* betas      = (const float*)d_in[0];
    const float* pose       = (const float*)d_in[1];
    const float* v_template = (const float*)d_in[2];
    const float* shapedirs  = (const float*)d_in[3];
    const float* posedirs   = (const float*)d_in[4];
    const float* Jreg       = (const float*)d_in[5];
    const float* lbs        = (const float*)d_in[6];

    float* ws   = (float*)d_ws;
    float* PFt  = ws + WS_PF;
    float* A    = ws + WS_A;
    float* EXT  = ws + WS_EXT;
    float* part = ws + WS_PART;

    float* verts = (float*)d_out;
    float* outJ  = verts + (size_t)B_N*V_N*3;

    hipLaunchKernelGGL(k_jreg, dim3(24,4), dim3(256), 0, stream, Jreg, v_template, shapedirs, part);
    hipLaunchKernelGGL(k_ext, dim3((NCOL+255)/256), dim3(256), 0, stream, shapedirs, v_template, EXT);
    hipLaunchKernelGGL(k_batch, dim3(256), dim3(64), 0, stream, pose, betas, part, PFt, A, outJ);
    hipLaunchKernelGGL(k_fused, dim3(8*108), dim3(256), 0, stream, posedirs, EXT, PFt, A, lbs, verts);
}